// Round 1
// baseline (317.931 us; speedup 1.0000x reference)
//
#include <hip/hip_runtime.h>
#include <hip/hip_bf16.h>
#include <stdint.h>

#define NT 16320      // 64 * 255
#define NTPAD 16384
#define KDIM 128      // padded from 100
#define NSEQ 64
#define TSTEPS 255
#define VOCAB 32000
#define EDIM 100
#define CHUNKS 17
#define CLEN 15       // 17*15 = 255

typedef __attribute__((ext_vector_type(8))) short s8v;
typedef __attribute__((ext_vector_type(4))) float f4v;

__device__ __forceinline__ float bflo(uint32_t u) { return __uint_as_float(u << 16); }
__device__ __forceinline__ float bfhi(uint32_t u) { return __uint_as_float(u & 0xffff0000u); }

// ---------------- fused: prep A+B (blocks 0..1279) + dkern (blocks 1280..1535)
__global__ __launch_bounds__(256) void prep_dk(const int* __restrict__ x,
                                               const float* __restrict__ emb,
                                               const float* __restrict__ Wt,
                                               const float* __restrict__ ec,
                                               const float* __restrict__ vw,
                                               __hip_bfloat16* __restrict__ A,
                                               __hip_bfloat16* __restrict__ B,
                                               float* __restrict__ partials) {
    int bid = blockIdx.x;
    int tid = threadIdx.x;
    if (bid < 1280) {
        int rloc = tid >> 4, q = tid & 15;
        int b = bid * 16 + rloc;
        int c0 = q * 8;
        float vals[8] = {0.f, 0.f, 0.f, 0.f, 0.f, 0.f, 0.f, 0.f};
        __hip_bfloat16* dst;
        if (b < NTPAD) {
            if (b < NT) {
                int n = b / TSTEPS;
                int t = b - n * TSTEPS;
                int tok = x[n * 256 + t];
                const float* er = emb + (size_t)tok * EDIM;
#pragma unroll
                for (int i = 0; i < 8; ++i) { int e = c0 + i; if (e < EDIM) vals[i] = er[e]; }
            }
            dst = A + (size_t)b * KDIM + c0;
        } else {
            int cc = b - NTPAD;
            const float* wr = Wt + (size_t)cc * EDIM;
#pragma unroll
            for (int i = 0; i < 8; ++i) { int e = c0 + i; if (e < EDIM) vals[i] = wr[e]; }
            dst = B + (size_t)cc * KDIM + c0;
        }
        union { __hip_bfloat16 h[8]; uint4 u; } pk;
#pragma unroll
        for (int i = 0; i < 8; ++i) pk.h[i] = __float2bfloat16(vals[i]);
        *(uint4*)dst = pk.u;
    } else {
        int db = bid - 1280;
        int wave = tid >> 6, lane = tid & 63;
        float er[64];
        {
            const float4* ecv = (const float4*)(ec + (size_t)lane * 64);
#pragma unroll
            for (int i = 0; i < 16; ++i) {
                float4 v = ecv[i];
                er[4 * i] = v.x; er[4 * i + 1] = v.y; er[4 * i + 2] = v.z; er[4 * i + 3] = v.w;
            }
        }
        int v0 = db * 125;
        float m = -1e30f, s = 0.f;
        for (int v = v0 + wave; v < v0 + 125; v += 4) {
            int vu = __builtin_amdgcn_readfirstlane(v);
            const float* row = vw + (size_t)vu * 64;
            float acc = 0.f;
#pragma unroll
            for (int e = 0; e < 64; ++e) acc += er[e] * row[e];
            float nm = fmaxf(m, acc);
            s = s * __expf(m - nm) + __expf(acc - nm);
            m = nm;
        }
        __shared__ float pm[4][64], ps[4][64];
        pm[wave][lane] = m; ps[wave][lane] = s;
        __syncthreads();
        if (tid < 64) {
            float M = pm[0][tid], Ssum = ps[0][tid];
#pragma unroll
            for (int w = 1; w < 4; ++w) {
                float m2 = pm[w][tid], s2 = ps[w][tid];
                float nm = fmaxf(M, m2);
                Ssum = Ssum * __expf(M - nm) + s2 * __expf(m2 - nm);
                M = nm;
            }
            partials[(db * 64 + tid) * 2]     = M;
            partials[(db * 64 + tid) * 2 + 1] = Ssum;
        }
    }
}

// ---------------- emissions (dreduce inlined): 8 tokens/wave ------------------
// pos(j) = ((j>>2)&3)*16 + ((j>>4)&3)*4 + (j&3)
__global__ __launch_bounds__(256) void emit_kern(const int* __restrict__ x,
                                                 const float* __restrict__ ec,
                                                 const float* __restrict__ vw,
                                                 const float* __restrict__ partials,
                                                 __hip_bfloat16* __restrict__ emB) {
    __shared__ float pm[4][64], ps[4][64], sD[64];
    int tid = threadIdx.x;
    int wave = tid >> 6, lane = tid & 63;

    {
        float M = -1e30f, S = 0.f;
        for (int b = wave; b < 256; b += 4) {
            float m2 = partials[(b * 64 + lane) * 2];
            float s2 = partials[(b * 64 + lane) * 2 + 1];
            float nm = fmaxf(M, m2);
            S = S * __expf(M - nm) + s2 * __expf(m2 - nm);
            M = nm;
        }
        pm[wave][lane] = M; ps[wave][lane] = S;
    }

    float er[64];
    {
        const float4* ecv = (const float4*)(ec + (size_t)lane * 64);
#pragma unroll
        for (int i = 0; i < 16; ++i) {
            float4 v = ecv[i];
            er[4 * i] = v.x; er[4 * i + 1] = v.y; er[4 * i + 2] = v.z; er[4 * i + 3] = v.w;
        }
    }
    __syncthreads();
    if (tid < 64) {
        float M = pm[0][tid], S = ps[0][tid];
#pragma unroll
        for (int w = 1; w < 4; ++w) {
            float m2 = pm[w][tid], s2 = ps[w][tid];
            float nm = fmaxf(M, m2);
            S = S * __expf(M - nm) + s2 * __expf(m2 - nm);
            M = nm;
        }
        sD[tid] = M + __logf(S);
    }
    __syncthreads();

    float dj = sD[lane];
    int j = lane;
    int pos = ((j >> 2) & 3) * 16 + ((j >> 4) & 3) * 4 + (j & 3);
    int nt0 = blockIdx.x * 32 + wave * 8;     // grid 510 -> 16320 exactly
#pragma unroll
    for (int s = 0; s < 8; ++s) {
        int nt = nt0 + s;
        int n = nt / TSTEPS;
        int t = nt - n * TSTEPS;
        int tok = x[n * 256 + t + 1];
        tok = __builtin_amdgcn_readfirstlane(tok);
        const float* row = vw + (size_t)tok * 64;
        float acc = 0.f;
#pragma unroll
        for (int e = 0; e < 64; ++e) acc += er[e] * row[e];
        emB[(size_t)nt * 64 + pos] = __float2bfloat16(__expf(acc - dj));
    }
}

// ---------------- fused generation + scan: one block per chunk ----------------
// LDS: sE  = 15 x 64x64 bf16 transition matrices (8192 B each), XOR-swizzled:
//            byte(t,c) = (t*8192 + c*2) ^ (((t ^ (c>>6)) & 7) << 4)
//      sGT = 64 x 144 B running-product G^T (row = output column)
// Phase 1 (all 4 waves): wave w generates c-groups [w*16, w*16+16):
//   MFMA( W-rows[c-group] , xe-rows[chunk] ) -> D col(l15)=t, row(g4*4+rr)=c_local
//   softmax over 64 c per (t, group) via in-lane 16 + shfl_xor(16,32), * em, -> sE.
// One __syncthreads. Phase 2: wave w evolves G columns [w*16, w*16+16) through the
// 15 steps INDEPENDENTLY (new_G[:,c] depends only on E and G[:,c]) -> no barriers.
__global__ __launch_bounds__(256, 1) void fused_kern(const __hip_bfloat16* __restrict__ A,
                                                     const __hip_bfloat16* __restrict__ B,
                                                     const __hip_bfloat16* __restrict__ emB,
                                                     __hip_bfloat16* __restrict__ Gout,
                                                     float* __restrict__ Rout,
                                                     float* __restrict__ out) {
    extern __shared__ __align__(16) char smem[];
    char* sE  = smem;             // 122880 B
    char* sGT = smem + 122880;    // 9216 B

    int tid = threadIdx.x;
    int wave = tid >> 6, lane = tid & 63;
    int l15 = lane & 15, g4 = lane >> 4;
    int id = blockIdx.x;                  // 0..1087
    if (id == 0 && tid == 0) *out = 0.f;  // zero for combine's atomics
    int n = (id * 3856) >> 16;            // id / 17 (magic, exact for id < 4096)
    int c = id - n * 17;
    int base_m = n * TSTEPS + c * CLEN;

    // identity init of G^T (wave 0; visibility covered by the post-gen barrier)
    if (wave == 0) {
        uint4 z = {0, 0, 0, 0};
#pragma unroll
        for (int i = 0; i < 8; ++i) *(uint4*)(sGT + lane * 144 + i * 16) = z;
        *(uint16_t*)(sGT + lane * 144 + lane * 2) = 0x3F80;   // bf16 1.0
    }

    // per-lane xe fragments (B-operand): row = base_m + l15 (l15==15 is a dummy
    // row; its results are never stored). A rows >= NT are zero-padded by prep.
    const char* Ac = (const char*)A;
    s8v bfx[4];
#pragma unroll
    for (int k32 = 0; k32 < 4; ++k32)
        bfx[k32] = *(const s8v*)(Ac + (size_t)(base_m + l15) * 256 + k32 * 64 + g4 * 16);

    // per-lane em values: emB row (base_m+l15), pos = g4*16 + jt*4 + rr <-> j = jt*16+g4*4+rr
    float em[16];
    {
        const char* ep = (const char*)emB + (size_t)(base_m + l15) * 128 + g4 * 32;
        uint4 e0 = *(const uint4*)ep;
        uint4 e1 = *(const uint4*)(ep + 16);
        const uint32_t* w0 = (const uint32_t*)&e0;
        const uint32_t* w1 = (const uint32_t*)&e1;
#pragma unroll
        for (int i = 0; i < 4; ++i) {
            em[2 * i] = bflo(w0[i]);     em[2 * i + 1] = bfhi(w0[i]);
            em[8 + 2 * i] = bflo(w1[i]); em[8 + 2 * i + 1] = bfhi(w1[i]);
        }
    }

    // ---- phase 1: generation -------------------------------------------------
    const char* Bc = (const char*)B;
    for (int grp = 0; grp < 16; ++grp) {
        int gidx = wave * 16 + grp;       // global c-group 0..63
        int cbase = gidx * 64;
        s8v af[4][4];
#pragma unroll
        for (int jt = 0; jt < 4; ++jt)
#pragma unroll
            for (int k32 = 0; k32 < 4; ++k32)
                af[jt][k32] = *(const s8v*)(Bc + (size_t)(cbase + jt * 16 + l15) * 256 + k32 * 64 + g4 * 16);
        f4v acc[4] = {};
#pragma unroll
        for (int k32 = 0; k32 < 4; ++k32)
#pragma unroll
            for (int jt = 0; jt < 4; ++jt)
                acc[jt] = __builtin_amdgcn_mfma_f32_16x16x32_bf16(af[jt][k32], bfx[k32], acc[jt], 0, 0, 0);

        // softmax over the 64 c's of this group, per row t=l15
        float v[16];
#pragma unroll
        for (int jt = 0; jt < 4; ++jt)
#pragma unroll
            for (int rr = 0; rr < 4; ++rr) v[jt * 4 + rr] = acc[jt][rr];
        float mx = v[0];
#pragma unroll
        for (int k = 1; k < 16; ++k) mx = fmaxf(mx, v[k]);
        mx = fmaxf(mx, __shfl_xor(mx, 16, 64));
        mx = fmaxf(mx, __shfl_xor(mx, 32, 64));
        float ex[16], sg = 0.f;
#pragma unroll
        for (int k = 0; k < 16; ++k) { ex[k] = __expf(v[k] - mx); sg += ex[k]; }
        sg += __shfl_xor(sg, 16, 64);
        sg += __shfl_xor(sg, 32, 64);
        float inv = 1.0f / sg;
        if (l15 < 15) {
            int swz = ((l15 ^ gidx) & 7) << 4;
#pragma unroll
            for (int jt = 0; jt < 4; ++jt) {
                union { __hip_bfloat16 h[4]; uint2 u; } pk;
#pragma unroll
                for (int rr = 0; rr < 4; ++rr)
                    pk.h[rr] = __float2bfloat16(ex[jt * 4 + rr] * inv * em[jt * 4 + rr]);
                int off = l15 * 8192 + (cbase + jt * 16 + g4 * 4) * 2;
                *(uint2*)(sE + (off ^ swz)) = pk.u;
            }
        }
    }
    __syncthreads();

    // ---- phase 2: scan (wave-independent, barrier-free) ----------------------
    int ct = wave;
    int colrow = (ct * 16 + l15) * 144;
    float rlog = 0.f;
    for (int tl = 14; tl >= 0; --tl) {
        int swz = ((tl ^ l15) & 7) << 4;
        s8v af[4][2];
#pragma unroll
        for (int at = 0; at < 4; ++at)
#pragma unroll
            for (int kk = 0; kk < 2; ++kk) {
                int off = tl * 8192 + (at * 16 + l15) * 128 + kk * 64 + g4 * 16;
                af[at][kk] = *(const s8v*)(sE + (off ^ swz));
            }
        s8v bG[2];
#pragma unroll
        for (int kk = 0; kk < 2; ++kk)
            bG[kk] = *(const s8v*)(sGT + colrow + kk * 64 + g4 * 16);
        f4v acc[4] = {};
#pragma unroll
        for (int kk = 0; kk < 2; ++kk)
#pragma unroll
            for (int at = 0; at < 4; ++at)
                acc[at] = __builtin_amdgcn_mfma_f32_16x16x32_bf16(af[at][kk], bG[kk], acc[at], 0, 0, 0);

        if (tl % 3 == 0) {
            // per-column max-normalize (bf16 exponent absorbs <=3 steps of decay)
            float mx = acc[0][0];
#pragma unroll
            for (int at = 0; at < 4; ++at)
#pragma unroll
                for (int rr = 0; rr < 4; ++rr) mx = fmaxf(mx, acc[at][rr]);
            mx = fmaxf(mx, __shfl_xor(mx, 16, 64));
            mx = fmaxf(mx, __shfl_xor(mx, 32, 64));
            mx = fmaxf(mx, 1e-38f);
            rlog += __logf(mx);
            float inv = 1.0f / mx;
#pragma unroll
            for (int at = 0; at < 4; ++at) {
                union { __hip_bfloat16 h[4]; uint2 u; } pk;
#pragma unroll
                for (int rr = 0; rr < 4; ++rr)
                    pk.h[rr] = __float2bfloat16(acc[at][rr] * inv);
                *(uint2*)(sGT + colrow + at * 32 + g4 * 8) = pk.u;
            }
        } else {
#pragma unroll
            for (int at = 0; at < 4; ++at) {
                union { __hip_bfloat16 h[4]; uint2 u; } pk;
#pragma unroll
                for (int rr = 0; rr < 4; ++rr)
                    pk.h[rr] = __float2bfloat16(acc[at][rr]);
                *(uint2*)(sGT + colrow + at * 32 + g4 * 8) = pk.u;
            }
        }
    }

    // ---- output: Gout[id*4096 + col*64 + a] = W[a][col] ----
    {
        char* go = (char*)(Gout + (size_t)id * 4096) + (ct * 16 + l15) * 128 + g4 * 32;
        const char* src = sGT + colrow + g4 * 32;
        *(uint4*)go        = *(const uint4*)src;
        *(uint4*)(go + 16) = *(const uint4*)(src + 16);
    }
    if (g4 == 0) Rout[(size_t)id * 64 + ct * 16 + l15] = rlog;
}

// ---------------- combine: ONE WAVE per sequence, barrier-free ----------------
__global__ __launch_bounds__(64) void combine_kern(const __hip_bfloat16* __restrict__ G,
                                                   const float* __restrict__ R,
                                                   const float* __restrict__ sw,
                                                   const float* __restrict__ sb,
                                                   float* __restrict__ out) {
    int n = blockIdx.x;
    int lane = threadIdx.x;
    __shared__ __align__(16) float sV[64];

    float alpha;
    {
        float v = sw[lane] + sb[lane];
        float m = v;
#pragma unroll
        for (int off = 1; off < 64; off <<= 1) m = fmaxf(m, __shfl_xor(m, off, 64));
        float s = __expf(v - m);
#pragma unroll
        for (int off = 1; off < 64; off <<= 1) s += __shfl_xor(s, off, 64);
        alpha = v - (m + __logf(s));
    }

    const char* Gb = (const char*)(G + (size_t)n * CHUNKS * 4096) + lane * 128;
    const float* Rb = R + (size_t)n * CHUNKS * 64 + lane;

    uint4 pf[8];
#pragma unroll
    for (int i = 0; i < 8; ++i) pf[i] = *(const uint4*)(Gb + i * 16);
    float rpf = Rb[0];

    for (int c = 0; c < CHUNKS; ++c) {
        uint4 cur[8];
#pragma unroll
        for (int i = 0; i < 8; ++i) cur[i] = pf[i];
        float rc = rpf;
        if (c + 1 < CHUNKS) {
            const char* gn = Gb + (size_t)(c + 1) * 8192;
#pragma unroll
            for (int i = 0; i < 8; ++i) pf[i] = *(const uint4*)(gn + i * 16);
            rpf = Rb[(c + 1) * 64];
        }

        float m = alpha;
#pragma unroll
        for (int off = 1; off < 64; off <<= 1) m = fmaxf(m, __shfl_xor(m, off, 64));
        sV[lane] = __expf(alpha - m);
        float acc = 0.f;
        const float4* sv4 = (const float4*)sV;
#pragma unroll
        for (int i = 0; i < 8; ++i) {
            const uint32_t* gw = (const uint32_t*)&cur[i];
            float4 va = sv4[2 * i], vb = sv4[2 * i + 1];
            acc += va.x * bflo(gw[0]) + va.y * bfhi(gw[0]);
            acc += va.z * bflo(gw[1]) + va.w * bfhi(gw[1]);
            acc += vb.x * bflo(gw[2]) + vb.y * bfhi(gw[2]);
            acc += vb.z * bflo(gw[3]) + vb.w * bfhi(gw[3]);
        }
        alpha = m + __logf(fmaxf(acc, 1e-38f)) + rc;
    }

    {
        float m = alpha;
#pragma unroll
        for (int off = 1; off < 64; off <<= 1) m = fmaxf(m, __shfl_xor(m, off, 64));
        float s = __expf(alpha - m);
#pragma unroll
        for (int off = 1; off < 64; off <<= 1) s += __shfl_xor(s, off, 64);
        if (lane == 0) atomicAdd(out, -(m + __logf(s)) * (1.0f / 64.0f));
    }
}

extern "C" void kernel_launch(void* const* d_in, const int* in_sizes, int n_in,
                              void* d_out, int out_size, void* d_ws, size_t ws_size,
                              hipStream_t stream) {
    const int*   x   = (const int*)d_in[0];
    const float* emb = (const float*)d_in[1];
    const float* Wt  = (const float*)d_in[2];
    const float* sw  = (const float*)d_in[3];
    const float* sb  = (const float*)d_in[4];
    const float* ec  = (const float*)d_in[5];
    const float* vw  = (const float*)d_in[6];
    float* out = (float*)d_out;
    char* ws = (char*)d_ws;

    __hip_bfloat16* A   = (__hip_bfloat16*)ws;                        //  4,194,304 B
    __hip_bfloat16* B   = (__hip_bfloat16*)(ws + 4194304ull);         //  1,048,576 B
    __hip_bfloat16* emB = (__hip_bfloat16*)(ws + 5242880ull);         //  2,097,152 B
    float* partials     = (float*)(ws + 7340032ull);                  //    131,072 B
    __hip_bfloat16* Gc  = (__hip_bfloat16*)(ws + 7471104ull);         //  8,912,896 B
    float* Rc           = (float*)(ws + 16384000ull);                 //    278,528 B

    static int ldsInit = 0;
    if (!ldsInit) {
        hipFuncSetAttribute((const void*)fused_kern,
                            hipFuncAttributeMaxDynamicSharedMemorySize, 132096);
        ldsInit = 1;
    }

    prep_dk<<<1536, 256, 0, stream>>>(x, emb, Wt, ec, vw, A, B, partials);
    emit_kern<<<510, 256, 0, stream>>>(x, ec, vw, partials, emB);
    fused_kern<<<NSEQ * CHUNKS, 256, 132096, stream>>>(A, B, emB, Gc, Rc, out);
    combine_kern<<<NSEQ, 64, 0, stream>>>(Gc, Rc, sw, sb, out);
}

// Round 2
// 316.918 us; speedup vs baseline: 1.0032x; 1.0032x over previous
//
#include <hip/hip_runtime.h>
#include <hip/hip_bf16.h>
#include <stdint.h>

#define NT 16320      // 64 * 255
#define NTPAD 16384
#define KDIM 128      // padded from 100
#define NSEQ 64
#define TSTEPS 255
#define VOCAB 32000
#define EDIM 100
#define CHUNKS 17
#define CLEN 15       // 17*15 = 255

typedef __attribute__((ext_vector_type(8))) short s8v;
typedef __attribute__((ext_vector_type(4))) float f4v;

__device__ __forceinline__ float bflo(uint32_t u) { return __uint_as_float(u << 16); }
__device__ __forceinline__ float bfhi(uint32_t u) { return __uint_as_float(u & 0xffff0000u); }

// async global->LDS, 16B per lane; lane i writes lds_base + i*16 (wave-uniform base)
__device__ __forceinline__ void load_lds16(const void* g, void* l) {
    __builtin_amdgcn_global_load_lds(
        (const __attribute__((address_space(1))) void*)(uintptr_t)g,
        (__attribute__((address_space(3))) void*)(uintptr_t)l,
        16, 0, 0);
}

// ---------------- K1: prep A+B (blocks 0..1279) + dkern exp-sums (1280..1535) --
// dkern: no max tracking. s = ec_j . vw_v has |s| <~ 26, exp(s) <= ~2e11, and
// sum over 32000 <= ~1e15 << f32 max -> direct exp-sum is safe and exact to 1e-7.
__global__ __launch_bounds__(256) void prep_dk(const int* __restrict__ x,
                                               const float* __restrict__ emb,
                                               const float* __restrict__ Wt,
                                               const float* __restrict__ ec,
                                               const float* __restrict__ vw,
                                               __hip_bfloat16* __restrict__ A,
                                               __hip_bfloat16* __restrict__ B,
                                               float* __restrict__ partials,
                                               int* __restrict__ cnt,
                                               float* __restrict__ out) {
    int bid = blockIdx.x;
    int tid = threadIdx.x;
    if (bid < 1280) {
        int rloc = tid >> 4, q = tid & 15;
        int b = bid * 16 + rloc;
        int c0 = q * 8;
        float vals[8] = {0.f, 0.f, 0.f, 0.f, 0.f, 0.f, 0.f, 0.f};
        __hip_bfloat16* dst;
        if (b < NTPAD) {
            if (b < NT) {
                int n = b / TSTEPS;
                int t = b - n * TSTEPS;
                int tok = x[n * 256 + t];
                const float* er = emb + (size_t)tok * EDIM;
#pragma unroll
                for (int i = 0; i < 8; ++i) { int e = c0 + i; if (e < EDIM) vals[i] = er[e]; }
            }
            dst = A + (size_t)b * KDIM + c0;
        } else {
            int cc = b - NTPAD;
            const float* wr = Wt + (size_t)cc * EDIM;
#pragma unroll
            for (int i = 0; i < 8; ++i) { int e = c0 + i; if (e < EDIM) vals[i] = wr[e]; }
            dst = B + (size_t)cc * KDIM + c0;
        }
        union { __hip_bfloat16 h[8]; uint4 u; } pk;
#pragma unroll
        for (int i = 0; i < 8; ++i) pk.h[i] = __float2bfloat16(vals[i]);
        *(uint4*)dst = pk.u;
    } else {
        int db = bid - 1280;
        int wave = tid >> 6, lane = tid & 63;
        if (db == 0 && tid < 64) {            // zero combine counters + output accum
            cnt[tid] = 0;
            if (tid == 0) *out = 0.f;
        }
        float er[64];
        {
            const float4* ecv = (const float4*)(ec + (size_t)lane * 64);
#pragma unroll
            for (int i = 0; i < 16; ++i) {
                float4 v = ecv[i];
                er[4 * i] = v.x; er[4 * i + 1] = v.y; er[4 * i + 2] = v.z; er[4 * i + 3] = v.w;
            }
        }
        int v0 = db * 125;
        float S = 0.f;
        for (int v = v0 + wave; v < v0 + 125; v += 4) {
            int vu = __builtin_amdgcn_readfirstlane(v);
            const float* row = vw + (size_t)vu * 64;
            float acc = 0.f;
#pragma unroll
            for (int e = 0; e < 64; ++e) acc += er[e] * row[e];
            S += __expf(acc);
        }
        __shared__ float ps[4][64];
        ps[wave][lane] = S;
        __syncthreads();
        if (tid < 64)
            partials[db * 64 + tid] = ps[0][tid] + ps[1][tid] + ps[2][tid] + ps[3][tid];
    }
}

// ---------------- K2: gemm (softmax only, NO em) + emit (blocks 4096..4605) ----
// gemm blocks: bid<4096 -> mblk=bid&127, nblk=bid>>7 (same order as old (128,32) grid).
// emit blocks are independent of gemm output (em is now applied in chunk_comb),
// so they can share the kernel and hide under the gemm blocks.
__global__ __launch_bounds__(256) void gemm_emit(const __hip_bfloat16* __restrict__ A,
                                                 const __hip_bfloat16* __restrict__ B,
                                                 const int* __restrict__ x,
                                                 const float* __restrict__ ec,
                                                 const float* __restrict__ vw,
                                                 const float* __restrict__ partials,
                                                 __hip_bfloat16* __restrict__ Eg,
                                                 __hip_bfloat16* __restrict__ emB) {
    __shared__ __align__(16) char smem[65536];
    int bid = blockIdx.x;
    int tid = threadIdx.x, wave = tid >> 6, lane = tid & 63;

    if (bid < 4096) {
        int mblk = bid & 127;    // 0..127 (128 m rows)
        int nblk = bid >> 7;     // 0..31  (128 c cols)
        char* sA = smem;            // 128 m-rows * 256 B
        char* sB = smem + 32768;    // 128 c-rows * 256 B

        // ---- stage ----
        {
            int r0 = wave * 32;
            int l16 = lane & 15;
            int rsub = lane >> 4;
#pragma unroll
            for (int g = 0; g < 8; ++g) {
                int r = r0 + g * 4 + rsub;
                int chunk = l16 ^ (r & 7);
                const char* gp = (const char*)(A + (size_t)(mblk * 128 + r) * KDIM) + chunk * 16;
                load_lds16(gp, sA + (r0 + g * 4) * 256);
            }
#pragma unroll
            for (int g = 0; g < 8; ++g) {
                int c = r0 + g * 4 + rsub;
                int chunk = l16 ^ (c & 7);
                const char* gp = (const char*)(B + (size_t)(nblk * 128 + c) * KDIM) + chunk * 16;
                load_lds16(gp, sB + (r0 + g * 4) * 256);
            }
        }
        __syncthreads();

        // ---- compute ----
        int wc = (wave >> 1) * 64, wm = (wave & 1) * 64;
        int l15 = lane & 15, g4 = lane >> 4;
        f4v acc[4][4] = {};   // [jt(c-tile)][mt(m-tile)]
#pragma unroll
        for (int k32 = 0; k32 < 4; ++k32) {
            s8v af[4], bf[4];
#pragma unroll
            for (int jt = 0; jt < 4; ++jt) {
                int r = wc + jt * 16 + l15;
                int chunk = (k32 * 4 + g4) ^ (r & 7);
                af[jt] = *(const s8v*)(sB + r * 256 + chunk * 16);
            }
#pragma unroll
            for (int mt = 0; mt < 4; ++mt) {
                int r = wm + mt * 16 + l15;
                int chunk = (k32 * 4 + g4) ^ (r & 7);
                bf[mt] = *(const s8v*)(sA + r * 256 + chunk * 16);
            }
#pragma unroll
            for (int jt = 0; jt < 4; ++jt)
#pragma unroll
                for (int mt = 0; mt < 4; ++mt)
                    acc[jt][mt] = __builtin_amdgcn_mfma_f32_16x16x32_bf16(af[jt], bf[mt], acc[jt][mt], 0, 0, 0);
        }
        __syncthreads();   // staging dead; reuse for sW

        // ---- epilogue: per col m: softmax over 64 j -> bf16 pack -> sW (no em) ----
        char* sW = smem;   // 128 m-rows * 272 B
#pragma unroll
        for (int mt = 0; mt < 4; ++mt) {
            int mrow = wm + mt * 16 + l15;
            float v[16];
#pragma unroll
            for (int jt = 0; jt < 4; ++jt)
#pragma unroll
                for (int rr = 0; rr < 4; ++rr) v[jt * 4 + rr] = acc[jt][mt][rr];
            float mx = v[0];
#pragma unroll
            for (int k = 1; k < 16; ++k) mx = fmaxf(mx, v[k]);
            mx = fmaxf(mx, __shfl_xor(mx, 16, 64));
            mx = fmaxf(mx, __shfl_xor(mx, 32, 64));
            float ex[16], sg = 0.f;
#pragma unroll
            for (int k = 0; k < 16; ++k) { ex[k] = __expf(v[k] - mx); sg += ex[k]; }
            sg += __shfl_xor(sg, 16, 64);
            sg += __shfl_xor(sg, 32, 64);
            float inv = 1.0f / sg;
#pragma unroll
            for (int jt = 0; jt < 4; ++jt) {
                union { __hip_bfloat16 h[4]; uint2 u; } pk;
#pragma unroll
                for (int rr = 0; rr < 4; ++rr)
                    pk.h[rr] = __float2bfloat16(ex[jt * 4 + rr] * inv);
                *(uint2*)(sW + mrow * 272 + (wc + jt * 16 + g4 * 4) * 2) = pk.u;
            }
        }
        __syncthreads();

        // ---- coalesced store ----
        {
            int rloc = tid >> 3;
            int q = tid & 7;
#pragma unroll
            for (int rp = 0; rp < 4; ++rp) {
                int row = rp * 32 + rloc;
                char* dst = (char*)Eg + (size_t)(mblk * 128 + row) * 8192 + nblk * 256;
                const char* src = sW + row * 272;
                *(uint4*)(dst + q * 16)       = *(const uint4*)(src + q * 16);
                *(uint4*)(dst + 128 + q * 16) = *(const uint4*)(src + 128 + q * 16);
            }
        }
    } else {
        // ---------------- emit ----------------
        int bid2 = bid - 4096;                  // 0..509
        float* sEC = (float*)smem;              // 64 x 65 f32 (pad 65 -> conflict-free)
        float* sP  = (float*)(smem + 16640);    // 4 x 64
        float* sD  = (float*)(smem + 17664);    // 64
        for (int i = tid; i < 4096; i += 256) {
            int r = i >> 6, cc = i & 63;
            sEC[r * 65 + cc] = ec[i];
        }
        // denominator: sum the 256 per-block exp-sums, then log
        float S = 0.f;
        for (int b = wave * 64; b < wave * 64 + 64; ++b) S += partials[b * 64 + lane];
        sP[wave * 64 + lane] = S;
        __syncthreads();
        if (tid < 64) sD[tid] = __logf(sP[tid] + sP[64 + tid] + sP[128 + tid] + sP[192 + tid]);
        __syncthreads();

        float dj = sD[lane];
        int j = lane;
        int pos = ((j >> 2) & 3) * 16 + ((j >> 4) & 3) * 4 + (j & 3);
        int nt0 = bid2 * 32 + wave * 8;         // 510*32 = 16320 exactly
#pragma unroll
        for (int s = 0; s < 8; ++s) {
            int nt = nt0 + s;
            int n = nt / TSTEPS;
            int t = nt - n * TSTEPS;
            int tok = x[n * 256 + t + 1];
            tok = __builtin_amdgcn_readfirstlane(tok);
            const float* row = vw + (size_t)tok * 64;
            float acc = 0.f;
#pragma unroll
            for (int e = 0; e < 64; ++e) acc += sEC[lane * 65 + e] * row[e];
            emB[(size_t)nt * 64 + pos] = __float2bfloat16(__expf(acc - dj));
        }
    }
}

// ---------------- K3: chunk scan (+ em row-scale) + inline combine -------------
// Eg now holds probs only. Product per chunk must equal M0*M1*...*M14 with
// Mt = Tt*diag(em_t):  init G = diag(em[14]); step tl computes T(tl)*G then
// row-scales by em[tl-1] at pack time (none at tl=0):
//   G_final = T0*D0*T1*D1*...*T14*D14 = M0*M1*...*M14   (exact).
// Last finishing block of each sequence runs the combine inline.
__global__ __launch_bounds__(64) void chunk_comb(const __hip_bfloat16* __restrict__ Eg,
                                                 const __hip_bfloat16* __restrict__ emB,
                                                 __hip_bfloat16* Gout,
                                                 float* Rout,
                                                 const float* __restrict__ sw,
                                                 const float* __restrict__ sb,
                                                 int* cnt,
                                                 float* out) {
    int lane = threadIdx.x;
    int l15 = lane & 15, g4 = lane >> 4;
    int id = blockIdx.x;               // 0..1087
    int n = (id * 3856) >> 16;         // id / 17
    int c = id - n * 17;
    int base_m = n * TSTEPS + c * CLEN;

    __shared__ __align__(16) char sGT[64 * 144];   // 9216 B

    // init G = diag(em[base_m+14]): sGT row `col` holds a-values; diag at a==col.
    {
        uint4 z = {0, 0, 0, 0};
#pragma unroll
        for (int i = 0; i < 8; ++i) *(uint4*)(sGT + lane * 144 + i * 16) = z;
        int pos_l = ((lane >> 2) & 3) * 16 + ((lane >> 4) & 3) * 4 + (lane & 3);
        *(uint16_t*)(sGT + lane * 144 + lane * 2) =
            *(const uint16_t*)((const char*)emB + (size_t)(base_m + 14) * 128 + pos_l * 2);
    }

    const char* Ebase = (const char*)Eg;
    uint4 pf[4][2];
    {
        const char* tp = Ebase + (size_t)(base_m + 14) * 8192;
#pragma unroll
        for (int at = 0; at < 4; ++at)
#pragma unroll
            for (int kk = 0; kk < 2; ++kk)
                pf[at][kk] = *(const uint4*)(tp + (at * 16 + l15) * 128 + kk * 64 + g4 * 16);
    }

    float rlog[4] = {0.f, 0.f, 0.f, 0.f};

    for (int tl = 14; tl >= 0; --tl) {
        uint4 af[4][2];
#pragma unroll
        for (int at = 0; at < 4; ++at) { af[at][0] = pf[at][0]; af[at][1] = pf[at][1]; }
        if (tl > 0) {
            const char* tp = Ebase + (size_t)(base_m + tl - 1) * 8192;
#pragma unroll
            for (int at = 0; at < 4; ++at)
#pragma unroll
                for (int kk = 0; kk < 2; ++kk)
                    pf[at][kk] = *(const uint4*)(tp + (at * 16 + l15) * 128 + kk * 64 + g4 * 16);
        }

        // em for this step's pack: row base_m+tl-1 (unused at tl==0)
        uint4 e0, e1;
        {
            int trow = base_m + (tl > 0 ? tl - 1 : 0);
            const char* ep = (const char*)emB + (size_t)trow * 128 + g4 * 32;
            e0 = *(const uint4*)ep;
            e1 = *(const uint4*)(ep + 16);
        }

        f4v acc[4][4] = {};   // [at(a-tile)][ct(col-tile)]
#pragma unroll
        for (int kk = 0; kk < 2; ++kk) {
#pragma unroll
            for (int ct = 0; ct < 4; ++ct) {
                s8v b = *(const s8v*)(sGT + (ct * 16 + l15) * 144 + kk * 64 + g4 * 16);
#pragma unroll
                for (int at = 0; at < 4; ++at)
                    acc[at][ct] = __builtin_amdgcn_mfma_f32_16x16x32_bf16(
                        *(const s8v*)&af[at][kk], b, acc[at][ct], 0, 0, 0);
            }
        }

        // unpack em (index k = at*4+rr; row a = at*16+g4*4+rr has pos = g4*16+k)
        float em[16];
        {
            const uint32_t* w0 = (const uint32_t*)&e0;
            const uint32_t* w1 = (const uint32_t*)&e1;
#pragma unroll
            for (int i = 0; i < 4; ++i) {
                em[2 * i] = bflo(w0[i]);     em[2 * i + 1] = bfhi(w0[i]);
                em[8 + 2 * i] = bflo(w1[i]); em[8 + 2 * i + 1] = bfhi(w1[i]);
            }
        }
        if (tl == 0) {
#pragma unroll
            for (int k = 0; k < 16; ++k) em[k] = 1.0f;
        }

        if (tl % 3 == 0) {
            // colmax-normalize (pre-em max; bf16 exponent absorbs <=3 steps of decay)
#pragma unroll
            for (int ct = 0; ct < 4; ++ct) {
                float mx = acc[0][ct][0];
#pragma unroll
                for (int at = 0; at < 4; ++at)
#pragma unroll
                    for (int rr = 0; rr < 4; ++rr) mx = fmaxf(mx, acc[at][ct][rr]);
                mx = fmaxf(mx, __shfl_xor(mx, 16, 64));
                mx = fmaxf(mx, __shfl_xor(mx, 32, 64));
                mx = fmaxf(mx, 1e-38f);
                rlog[ct] += __logf(mx);
                float inv = 1.0f / mx;
                int col = ct * 16 + l15;
#pragma unroll
                for (int at = 0; at < 4; ++at) {
                    union { __hip_bfloat16 h[4]; uint2 u; } pk;
#pragma unroll
                    for (int rr = 0; rr < 4; ++rr)
                        pk.h[rr] = __float2bfloat16(acc[at][ct][rr] * inv * em[at * 4 + rr]);
                    *(uint2*)(sGT + col * 144 + at * 32 + g4 * 8) = pk.u;
                }
            }
        } else {
#pragma unroll
            for (int ct = 0; ct < 4; ++ct) {
                int col = ct * 16 + l15;
#pragma unroll
                for (int at = 0; at < 4; ++at) {
                    union { __hip_bfloat16 h[4]; uint2 u; } pk;
#pragma unroll
                    for (int rr = 0; rr < 4; ++rr)
                        pk.h[rr] = __float2bfloat16(acc[at][ct][rr] * em[at * 4 + rr]);
                    *(uint2*)(sGT + col * 144 + at * 32 + g4 * 8) = pk.u;
                }
            }
        }
    }

    // ---- outputs ----
    {
        char* go = (char*)(Gout + (size_t)id * 4096 + lane * 64);
#pragma unroll
        for (int i = 0; i < 8; ++i)
            *(uint4*)(go + i * 16) = *(const uint4*)(sGT + lane * 144 + i * 16);
    }
    if (g4 == 0)
#pragma unroll
        for (int ct = 0; ct < 4; ++ct)
            Rout[(size_t)id * 64 + ct * 16 + l15] = rlog[ct];

    // ---- last block of this sequence runs the combine inline ----
    __threadfence();
    int old = 0;
    if (lane == 0) old = atomicAdd(&cnt[n], 1);
    old = __shfl(old, 0, 64);
    if (old != CHUNKS - 1) return;
    __threadfence();   // acquire: other chunks' Gout/Rout now visible

    float* sV = (float*)sGT;   // reuse LDS

    float alpha;
    {
        float v = sw[lane] + sb[lane];
        float m = v;
#pragma unroll
        for (int off = 1; off < 64; off <<= 1) m = fmaxf(m, __shfl_xor(m, off, 64));
        float s = __expf(v - m);
#pragma unroll
        for (int off = 1; off < 64; off <<= 1) s += __shfl_xor(s, off, 64);
        alpha = v - (m + __logf(s));
    }

    const char* Gb = (const char*)(Gout + (size_t)n * CHUNKS * 4096) + lane * 128;
    const float* Rb = Rout + (size_t)n * CHUNKS * 64 + lane;

    uint4 pfc[8];
#pragma unroll
    for (int i = 0; i < 8; ++i) pfc[i] = *(const uint4*)(Gb + i * 16);
    float rpf = Rb[0];

    for (int cc = 0; cc < CHUNKS; ++cc) {
        uint4 cur[8];
#pragma unroll
        for (int i = 0; i < 8; ++i) cur[i] = pfc[i];
        float rc = rpf;
        if (cc + 1 < CHUNKS) {
            const char* gn = Gb + (size_t)(cc + 1) * 8192;
#pragma unroll
            for (int i = 0; i < 8; ++i) pfc[i] = *(const uint4*)(gn + i * 16);
            rpf = Rb[(cc + 1) * 64];
        }

        float m = alpha;
#pragma unroll
        for (int off = 1; off < 64; off <<= 1) m = fmaxf(m, __shfl_xor(m, off, 64));
        sV[lane] = __expf(alpha - m);
        float acc2 = 0.f;
        const float4* sv4 = (const float4*)sV;
#pragma unroll
        for (int i = 0; i < 8; ++i) {
            const uint32_t* gw = (const uint32_t*)&cur[i];
            float4 va = sv4[2 * i], vb = sv4[2 * i + 1];
            acc2 += va.x * bflo(gw[0]) + va.y * bfhi(gw[0]);
            acc2 += va.z * bflo(gw[1]) + va.w * bfhi(gw[1]);
            acc2 += vb.x * bflo(gw[2]) + vb.y * bfhi(gw[2]);
            acc2 += vb.z * bflo(gw[3]) + vb.w * bfhi(gw[3]);
        }
        alpha = m + __logf(fmaxf(acc2, 1e-38f)) + rc;
    }

    {
        float m = alpha;
#pragma unroll
        for (int off = 1; off < 64; off <<= 1) m = fmaxf(m, __shfl_xor(m, off, 64));
        float s = __expf(alpha - m);
#pragma unroll
        for (int off = 1; off < 64; off <<= 1) s += __shfl_xor(s, off, 64);
        if (lane == 0) atomicAdd(out, -(m + __logf(s)) * (1.0f / 64.0f));
    }
}

extern "C" void kernel_launch(void* const* d_in, const int* in_sizes, int n_in,
                              void* d_out, int out_size, void* d_ws, size_t ws_size,
                              hipStream_t stream) {
    const int*   x   = (const int*)d_in[0];
    const float* emb = (const float*)d_in[1];
    const float* Wt  = (const float*)d_in[2];
    const float* sw  = (const float*)d_in[3];
    const float* sb  = (const float*)d_in[4];
    const float* ec  = (const float*)d_in[5];
    const float* vw  = (const float*)d_in[6];
    float* out = (float*)d_out;
    char* ws = (char*)d_ws;

    __hip_bfloat16* Eg  = (__hip_bfloat16*)ws;                         // 134,217,728 B
    __hip_bfloat16* A   = (__hip_bfloat16*)(ws + 134217728ull);        //   4,194,304 B
    __hip_bfloat16* B   = (__hip_bfloat16*)(ws + 138412032ull);        //   1,048,576 B
    __hip_bfloat16* emB = (__hip_bfloat16*)(ws + 139460608ull);        //   2,097,152 B
    float* partials     = (float*)(ws + 141557760ull);                 //      65,536 B
    __hip_bfloat16* Gc  = (__hip_bfloat16*)(ws + 141623296ull);        //   8,912,896 B
    float* Rc           = (float*)(ws + 150536192ull);                 //     278,528 B
    int*   cnt          = (int*)(ws + 150814720ull);                   //         256 B

    prep_dk<<<1536, 256, 0, stream>>>(x, emb, Wt, ec, vw, A, B, partials, cnt, out);
    gemm_emit<<<4606, 256, 0, stream>>>(A, B, x, ec, vw, partials, Eg, emB);
    chunk_comb<<<1088, 64, 0, stream>>>(Eg, emB, Gc, Rc, sw, sb, cnt, out);
}

// Round 3
// 208.462 us; speedup vs baseline: 1.5251x; 1.5203x over previous
//
#include <hip/hip_runtime.h>
#include <hip/hip_bf16.h>
#include <stdint.h>

#define NT 16320      // 64 * 255
#define NTPAD 16384
#define KDIM 128      // padded from 100
#define NCOLS 4096    // K*K
#define NSEQ 64
#define TSTEPS 255
#define VOCAB 32000
#define EDIM 100
#define CHUNKS 17
#define CLEN 15       // 17*15 = 255

typedef __attribute__((ext_vector_type(8))) short s8v;
typedef __attribute__((ext_vector_type(4))) float f4v;

__device__ __forceinline__ float bflo(uint32_t u) { return __uint_as_float(u << 16); }
__device__ __forceinline__ float bfhi(uint32_t u) { return __uint_as_float(u & 0xffff0000u); }

// async global->LDS, 16B per lane; lane i writes lds_base + i*16 (wave-uniform base)
__device__ __forceinline__ void load_lds16(const void* g, void* l) {
    __builtin_amdgcn_global_load_lds(
        (const __attribute__((address_space(1))) void*)(uintptr_t)g,
        (__attribute__((address_space(3))) void*)(uintptr_t)l,
        16, 0, 0);
}

// ---------------- fused: prep A+B (blocks 0..1279) + dkern (blocks 1280..1535)
__global__ __launch_bounds__(256) void prep_dk(const int* __restrict__ x,
                                               const float* __restrict__ emb,
                                               const float* __restrict__ Wt,
                                               const float* __restrict__ ec,
                                               const float* __restrict__ vw,
                                               __hip_bfloat16* __restrict__ A,
                                               __hip_bfloat16* __restrict__ B,
                                               float* __restrict__ partials) {
    int bid = blockIdx.x;
    int tid = threadIdx.x;
    if (bid < 1280) {
        int rloc = tid >> 4, q = tid & 15;
        int b = bid * 16 + rloc;
        int c0 = q * 8;
        float vals[8] = {0.f, 0.f, 0.f, 0.f, 0.f, 0.f, 0.f, 0.f};
        __hip_bfloat16* dst;
        if (b < NTPAD) {
            if (b < NT) {
                int n = b / TSTEPS;
                int t = b - n * TSTEPS;
                int tok = x[n * 256 + t];
                const float* er = emb + (size_t)tok * EDIM;
#pragma unroll
                for (int i = 0; i < 8; ++i) { int e = c0 + i; if (e < EDIM) vals[i] = er[e]; }
            }
            dst = A + (size_t)b * KDIM + c0;
        } else {
            int cc = b - NTPAD;
            const float* wr = Wt + (size_t)cc * EDIM;
#pragma unroll
            for (int i = 0; i < 8; ++i) { int e = c0 + i; if (e < EDIM) vals[i] = wr[e]; }
            dst = B + (size_t)cc * KDIM + c0;
        }
        union { __hip_bfloat16 h[8]; uint4 u; } pk;
#pragma unroll
        for (int i = 0; i < 8; ++i) pk.h[i] = __float2bfloat16(vals[i]);
        *(uint4*)dst = pk.u;
    } else {
        int db = bid - 1280;
        int wave = tid >> 6, lane = tid & 63;
        float er[64];
        {
            const float4* ecv = (const float4*)(ec + (size_t)lane * 64);
#pragma unroll
            for (int i = 0; i < 16; ++i) {
                float4 v = ecv[i];
                er[4 * i] = v.x; er[4 * i + 1] = v.y; er[4 * i + 2] = v.z; er[4 * i + 3] = v.w;
            }
        }
        int v0 = db * 125;
        float m = -1e30f, s = 0.f;
        for (int v = v0 + wave; v < v0 + 125; v += 4) {
            int vu = __builtin_amdgcn_readfirstlane(v);
            const float* row = vw + (size_t)vu * 64;
            float acc = 0.f;
#pragma unroll
            for (int e = 0; e < 64; ++e) acc += er[e] * row[e];
            float nm = fmaxf(m, acc);
            s = s * __expf(m - nm) + __expf(acc - nm);
            m = nm;
        }
        __shared__ float pm[4][64], ps[4][64];
        pm[wave][lane] = m; ps[wave][lane] = s;
        __syncthreads();
        if (tid < 64) {
            float M = pm[0][tid], Ssum = ps[0][tid];
#pragma unroll
            for (int w = 1; w < 4; ++w) {
                float m2 = pm[w][tid], s2 = ps[w][tid];
                float nm = fmaxf(M, m2);
                Ssum = Ssum * __expf(M - nm) + s2 * __expf(m2 - nm);
                M = nm;
            }
            partials[(db * 64 + tid) * 2]     = M;
            partials[(db * 64 + tid) * 2 + 1] = Ssum;
        }
    }
}

// ---------------- emissions (dreduce inlined): 8 tokens/wave ------------------
// pos(j) = ((j>>2)&3)*16 + ((j>>4)&3)*4 + (j&3)
__global__ __launch_bounds__(256) void emit_kern(const int* __restrict__ x,
                                                 const float* __restrict__ ec,
                                                 const float* __restrict__ vw,
                                                 const float* __restrict__ partials,
                                                 __hip_bfloat16* __restrict__ emB) {
    __shared__ float pm[4][64], ps[4][64], sD[64];
    int tid = threadIdx.x;
    int wave = tid >> 6, lane = tid & 63;

    {
        float M = -1e30f, S = 0.f;
        for (int b = wave; b < 256; b += 4) {
            float m2 = partials[(b * 64 + lane) * 2];
            float s2 = partials[(b * 64 + lane) * 2 + 1];
            float nm = fmaxf(M, m2);
            S = S * __expf(M - nm) + s2 * __expf(m2 - nm);
            M = nm;
        }
        pm[wave][lane] = M; ps[wave][lane] = S;
    }

    float er[64];
    {
        const float4* ecv = (const float4*)(ec + (size_t)lane * 64);
#pragma unroll
        for (int i = 0; i < 16; ++i) {
            float4 v = ecv[i];
            er[4 * i] = v.x; er[4 * i + 1] = v.y; er[4 * i + 2] = v.z; er[4 * i + 3] = v.w;
        }
    }
    __syncthreads();
    if (tid < 64) {
        float M = pm[0][tid], S = ps[0][tid];
#pragma unroll
        for (int w = 1; w < 4; ++w) {
            float m2 = pm[w][tid], s2 = ps[w][tid];
            float nm = fmaxf(M, m2);
            S = S * __expf(M - nm) + s2 * __expf(m2 - nm);
            M = nm;
        }
        sD[tid] = M + __logf(S);
    }
    __syncthreads();

    float dj = sD[lane];
    int j = lane;
    int pos = ((j >> 2) & 3) * 16 + ((j >> 4) & 3) * 4 + (j & 3);
    int nt0 = blockIdx.x * 32 + wave * 8;     // grid 510 -> 16320 exactly
#pragma unroll
    for (int s = 0; s < 8; ++s) {
        int nt = nt0 + s;
        int n = nt / TSTEPS;
        int t = nt - n * TSTEPS;
        int tok = x[n * 256 + t + 1];
        tok = __builtin_amdgcn_readfirstlane(tok);
        const float* row = vw + (size_t)tok * 64;
        float acc = 0.f;
#pragma unroll
        for (int e = 0; e < 64; ++e) acc += er[e] * row[e];
        emB[(size_t)nt * 64 + pos] = __float2bfloat16(__expf(acc - dj));
    }
}

// ---------------- GEMM + softmax*em -> bf16 E ---------------------------------
// 128m x 64c tile, 48KB LDS -> 3 blocks/CU (was 128x128 @ 64KB -> 2 blocks/CU).
// Softmax group = 64 c = exactly one block's c-extent, so reduction stays
// in-wave (16 in-lane + shfl 16,32). No max-subtraction: |logit| <= ~58 so
// exp sums stay < 1e19 << f32 max; mathematically identical.
__global__ __launch_bounds__(256, 3) void gemm_kern(const __hip_bfloat16* __restrict__ A,
                                                    const __hip_bfloat16* __restrict__ B,
                                                    const __hip_bfloat16* __restrict__ emB,
                                                    __hip_bfloat16* __restrict__ Eg) {
    int mblk = blockIdx.x;   // 0..127 (128 m rows)
    int nblk = blockIdx.y;   // 0..63  (64 c cols = 1 softmax group)
    int tid = threadIdx.x, wave = tid >> 6, lane = tid & 63;

    __shared__ __align__(16) char smem[49152];
    char* sA = smem;            // 128 m-rows * 256 B = 32768
    char* sB = smem + 32768;    //  64 c-rows * 256 B = 16384

    // ---- stage ----
    {
        int l16 = lane & 15;
        int rsub = lane >> 4;
        int r0 = wave * 32;
#pragma unroll
        for (int g = 0; g < 8; ++g) {
            int r = r0 + g * 4 + rsub;
            int chunk = l16 ^ (r & 7);
            const char* gp = (const char*)(A + (size_t)(mblk * 128 + r) * KDIM) + chunk * 16;
            load_lds16(gp, sA + (r0 + g * 4) * 256);
        }
        int rb0 = wave * 16;
#pragma unroll
        for (int g = 0; g < 4; ++g) {
            int r = rb0 + g * 4 + rsub;
            int chunk = l16 ^ (r & 7);
            const char* gp = (const char*)(B + (size_t)(nblk * 64 + r) * KDIM) + chunk * 16;
            load_lds16(gp, sB + (rb0 + g * 4) * 256);
        }
    }
    __syncthreads();

    // ---- compute: A-operand = W rows (c), B-operand = xe rows (m) ----
    int wm = wave * 32;          // wave owns 32 m-rows x 64 c
    int l15 = lane & 15, g4 = lane >> 4;
    f4v acc[4][2] = {};   // [jt(c-tile)][mt(m-tile)]
#pragma unroll
    for (int k32 = 0; k32 < 4; ++k32) {
        s8v af[4], bf[2];
#pragma unroll
        for (int jt = 0; jt < 4; ++jt) {
            int r = jt * 16 + l15;
            int chunk = (k32 * 4 + g4) ^ (r & 7);
            af[jt] = *(const s8v*)(sB + r * 256 + chunk * 16);
        }
#pragma unroll
        for (int mt = 0; mt < 2; ++mt) {
            int r = wm + mt * 16 + l15;
            int chunk = (k32 * 4 + g4) ^ (r & 7);
            bf[mt] = *(const s8v*)(sA + r * 256 + chunk * 16);
        }
#pragma unroll
        for (int jt = 0; jt < 4; ++jt)
#pragma unroll
            for (int mt = 0; mt < 2; ++mt)
                acc[jt][mt] = __builtin_amdgcn_mfma_f32_16x16x32_bf16(af[jt], bf[mt], acc[jt][mt], 0, 0, 0);
    }
    __syncthreads();   // staging dead; reuse for sW

    // ---- epilogue: per col m: softmax over 64 j (no max), * em, bf16 -> sW ----
    char* sW = smem;   // 128 m-rows * 144 B (128 data + 16 pad)
    const char* emb8 = (const char*)emB;
#pragma unroll
    for (int mt = 0; mt < 2; ++mt) {
        int mrow = wm + mt * 16 + l15;
        int mglob = mblk * 128 + mrow;
        float ex[16], sg = 0.f;
#pragma unroll
        for (int jt = 0; jt < 4; ++jt)
#pragma unroll
            for (int rr = 0; rr < 4; ++rr) {
                float e = __expf(acc[jt][mt][rr]);
                ex[jt * 4 + rr] = e; sg += e;
            }
        sg += __shfl_xor(sg, 16, 64);
        sg += __shfl_xor(sg, 32, 64);
        float inv = 1.0f / sg;
        uint4 e0 = *(const uint4*)(emb8 + (size_t)mglob * 128 + g4 * 32);
        uint4 e1 = *(const uint4*)(emb8 + (size_t)mglob * 128 + g4 * 32 + 16);
        float em[16];
        {
            const uint32_t* w0 = (const uint32_t*)&e0;
            const uint32_t* w1 = (const uint32_t*)&e1;
#pragma unroll
            for (int i = 0; i < 4; ++i) {
                em[2 * i] = bflo(w0[i]);     em[2 * i + 1] = bfhi(w0[i]);
                em[8 + 2 * i] = bflo(w1[i]); em[8 + 2 * i + 1] = bfhi(w1[i]);
            }
        }
#pragma unroll
        for (int jt = 0; jt < 4; ++jt) {
            union { __hip_bfloat16 h[4]; uint2 u; } pk;
#pragma unroll
            for (int rr = 0; rr < 4; ++rr)
                pk.h[rr] = __float2bfloat16(ex[jt * 4 + rr] * inv * em[jt * 4 + rr]);
            *(uint2*)(sW + mrow * 144 + (jt * 16 + g4 * 4) * 2) = pk.u;
        }
    }
    __syncthreads();

    // ---- coalesced store: 8 lanes cover one 128B row; 8 rows per wave-instr ----
    {
        int rloc = tid >> 3;          // 0..31
        int q = tid & 7;              // 16 B chunk within the 128 B row
#pragma unroll
        for (int rp = 0; rp < 4; ++rp) {
            int row = rp * 32 + rloc;
            char* dst = (char*)Eg + (size_t)(mblk * 128 + row) * 8192 + nblk * 128;
            *(uint4*)(dst + q * 16) = *(const uint4*)(sW + row * 144 + q * 16);
        }
    }
}

// ---------------- chunk: one wave per chunk, norm every 3 steps ---------------
__global__ __launch_bounds__(64) void chunk_kern(const __hip_bfloat16* __restrict__ Eg,
                                                 __hip_bfloat16* __restrict__ Gout,
                                                 float* __restrict__ Rout,
                                                 float* __restrict__ out) {
    int lane = threadIdx.x;
    if (blockIdx.x == 0 && lane == 0) *out = 0.f;   // zero for combine's atomics
    int l15 = lane & 15, g4 = lane >> 4;
    int id = blockIdx.x;               // 0..1087
    int n = (id * 3856) >> 16;         // id / 17 (magic, exact for id < 4096)
    int c = id - n * 17;
    int base_m = n * TSTEPS + c * CLEN;

    __shared__ __align__(16) char sGT[64 * 144];   // 9216 B

    // init identity: lane owns row (= column) `lane`
    {
        uint4 z = {0, 0, 0, 0};
#pragma unroll
        for (int i = 0; i < 8; ++i) *(uint4*)(sGT + lane * 144 + i * 16) = z;
        *(uint16_t*)(sGT + lane * 144 + lane * 2) = 0x3F80;   // bf16 1.0
    }

    const char* Ebase = (const char*)Eg;
    uint4 pf[4][2];
    {
        const char* tp = Ebase + (size_t)(base_m + 14) * 8192;
#pragma unroll
        for (int at = 0; at < 4; ++at)
#pragma unroll
            for (int kk = 0; kk < 2; ++kk)
                pf[at][kk] = *(const uint4*)(tp + (at * 16 + l15) * 128 + kk * 64 + g4 * 16);
    }

    float rlog[4] = {0.f, 0.f, 0.f, 0.f};

    for (int tl = 14; tl >= 0; --tl) {
        uint4 af[4][2];
#pragma unroll
        for (int at = 0; at < 4; ++at) { af[at][0] = pf[at][0]; af[at][1] = pf[at][1]; }
        if (tl > 0) {
            const char* tp = Ebase + (size_t)(base_m + tl - 1) * 8192;
#pragma unroll
            for (int at = 0; at < 4; ++at)
#pragma unroll
                for (int kk = 0; kk < 2; ++kk)
                    pf[at][kk] = *(const uint4*)(tp + (at * 16 + l15) * 128 + kk * 64 + g4 * 16);
        }

        f4v acc[4][4] = {};   // [at(m-tile)][ct(n-tile)]
#pragma unroll
        for (int kk = 0; kk < 2; ++kk) {
#pragma unroll
            for (int ct = 0; ct < 4; ++ct) {
                s8v b = *(const s8v*)(sGT + (ct * 16 + l15) * 144 + kk * 64 + g4 * 16);
#pragma unroll
                for (int at = 0; at < 4; ++at)
                    acc[at][ct] = __builtin_amdgcn_mfma_f32_16x16x32_bf16(
                        *(const s8v*)&af[at][kk], b, acc[at][ct], 0, 0, 0);
            }
        }

        if (tl % 3 == 0) {
            // full colmax-normalize (bf16 exponent absorbs <=3 steps of decay)
#pragma unroll
            for (int ct = 0; ct < 4; ++ct) {
                float mx = acc[0][ct][0];
#pragma unroll
                for (int at = 0; at < 4; ++at)
#pragma unroll
                    for (int rr = 0; rr < 4; ++rr) mx = fmaxf(mx, acc[at][ct][rr]);
                mx = fmaxf(mx, __shfl_xor(mx, 16, 64));
                mx = fmaxf(mx, __shfl_xor(mx, 32, 64));
                mx = fmaxf(mx, 1e-38f);
                rlog[ct] += __logf(mx);
                float inv = 1.0f / mx;
                int col = ct * 16 + l15;
#pragma unroll
                for (int at = 0; at < 4; ++at) {
                    union { __hip_bfloat16 h[4]; uint2 u; } pk;
#pragma unroll
                    for (int rr = 0; rr < 4; ++rr)
                        pk.h[rr] = __float2bfloat16(acc[at][ct][rr] * inv);
                    *(uint2*)(sGT + col * 144 + at * 32 + g4 * 8) = pk.u;
                }
            }
        } else {
            // direct pack, no normalization
#pragma unroll
            for (int ct = 0; ct < 4; ++ct) {
                int col = ct * 16 + l15;
#pragma unroll
                for (int at = 0; at < 4; ++at) {
                    union { __hip_bfloat16 h[4]; uint2 u; } pk;
#pragma unroll
                    for (int rr = 0; rr < 4; ++rr)
                        pk.h[rr] = __float2bfloat16(acc[at][ct][rr]);
                    *(uint2*)(sGT + col * 144 + at * 32 + g4 * 8) = pk.u;
                }
            }
        }
    }

    // ---- output: Gout[id*4096 + c*64 + a] = W[a][c]; lane -> col = lane ----
    {
        char* go = (char*)(Gout + (size_t)id * 4096 + lane * 64);
#pragma unroll
        for (int i = 0; i < 8; ++i)
            *(uint4*)(go + i * 16) = *(const uint4*)(sGT + lane * 144 + i * 16);
    }
    if (g4 == 0)
#pragma unroll
        for (int ct = 0; ct < 4; ++ct)
            Rout[(size_t)id * 64 + ct * 16 + l15] = rlog[ct];
}

// ---------------- combine: ONE WAVE per sequence, barrier-free ----------------
__global__ __launch_bounds__(64) void combine_kern(const __hip_bfloat16* __restrict__ G,
                                                   const float* __restrict__ R,
                                                   const float* __restrict__ sw,
                                                   const float* __restrict__ sb,
                                                   float* __restrict__ out) {
    int n = blockIdx.x;
    int lane = threadIdx.x;
    __shared__ __align__(16) float sV[64];

    float alpha;
    {
        float v = sw[lane] + sb[lane];
        float m = v;
#pragma unroll
        for (int off = 1; off < 64; off <<= 1) m = fmaxf(m, __shfl_xor(m, off, 64));
        float s = __expf(v - m);
#pragma unroll
        for (int off = 1; off < 64; off <<= 1) s += __shfl_xor(s, off, 64);
        alpha = v - (m + __logf(s));
    }

    const char* Gb = (const char*)(G + (size_t)n * CHUNKS * 4096) + lane * 128;
    const float* Rb = R + (size_t)n * CHUNKS * 64 + lane;

    uint4 pf[8];
#pragma unroll
    for (int i = 0; i < 8; ++i) pf[i] = *(const uint4*)(Gb + i * 16);
    float rpf = Rb[0];

    for (int c = 0; c < CHUNKS; ++c) {
        uint4 cur[8];
#pragma unroll
        for (int i = 0; i < 8; ++i) cur[i] = pf[i];
        float rc = rpf;
        if (c + 1 < CHUNKS) {
            const char* gn = Gb + (size_t)(c + 1) * 8192;
#pragma unroll
            for (int i = 0; i < 8; ++i) pf[i] = *(const uint4*)(gn + i * 16);
            rpf = Rb[(c + 1) * 64];
        }

        float m = alpha;
#pragma unroll
        for (int off = 1; off < 64; off <<= 1) m = fmaxf(m, __shfl_xor(m, off, 64));
        sV[lane] = __expf(alpha - m);
        float acc = 0.f;
        const float4* sv4 = (const float4*)sV;
#pragma unroll
        for (int i = 0; i < 8; ++i) {
            const uint32_t* gw = (const uint32_t*)&cur[i];
            float4 va = sv4[2 * i], vb = sv4[2 * i + 1];
            acc += va.x * bflo(gw[0]) + va.y * bfhi(gw[0]);
            acc += va.z * bflo(gw[1]) + va.w * bfhi(gw[1]);
            acc += vb.x * bflo(gw[2]) + vb.y * bfhi(gw[2]);
            acc += vb.z * bflo(gw[3]) + vb.w * bfhi(gw[3]);
        }
        alpha = m + __logf(fmaxf(acc, 1e-38f)) + rc;
    }

    {
        float m = alpha;
#pragma unroll
        for (int off = 1; off < 64; off <<= 1) m = fmaxf(m, __shfl_xor(m, off, 64));
        float s = __expf(alpha - m);
#pragma unroll
        for (int off = 1; off < 64; off <<= 1) s += __shfl_xor(s, off, 64);
        if (lane == 0) atomicAdd(out, -(m + __logf(s)) * (1.0f / 64.0f));
    }
}

extern "C" void kernel_launch(void* const* d_in, const int* in_sizes, int n_in,
                              void* d_out, int out_size, void* d_ws, size_t ws_size,
                              hipStream_t stream) {
    const int*   x   = (const int*)d_in[0];
    const float* emb = (const float*)d_in[1];
    const float* Wt  = (const float*)d_in[2];
    const float* sw  = (const float*)d_in[3];
    const float* sb  = (const float*)d_in[4];
    const float* ec  = (const float*)d_in[5];
    const float* vw  = (const float*)d_in[6];
    float* out = (float*)d_out;
    char* ws = (char*)d_ws;

    __hip_bfloat16* Eg  = (__hip_bfloat16*)ws;                         // 134,217,728 B
    __hip_bfloat16* A   = (__hip_bfloat16*)(ws + 134217728ull);        //   4,194,304 B
    __hip_bfloat16* B   = (__hip_bfloat16*)(ws + 138412032ull);        //   1,048,576 B
    __hip_bfloat16* emB = (__hip_bfloat16*)(ws + 139460608ull);        //   2,097,152 B
    float* partials     = (float*)(ws + 141557760ull);                 //     131,072 B
    __hip_bfloat16* Gc  = (__hip_bfloat16*)(ws + 141688832ull);        //   8,912,896 B
    float* Rc           = (float*)(ws + 150601728ull);                 //     278,528 B

    prep_dk<<<1536, 256, 0, stream>>>(x, emb, Wt, ec, vw, A, B, partials);
    emit_kern<<<510, 256, 0, stream>>>(x, ec, vw, partials, emB);
    gemm_kern<<<dim3(128, 64), 256, 0, stream>>>(A, B, emB, Eg);
    chunk_kern<<<NSEQ * CHUNKS, 64, 0, stream>>>(Eg, Gc, Rc, out);
    combine_kern<<<NSEQ, 64, 0, stream>>>(Gc, Rc, sw, sb, out);
}